// Round 1
// baseline (568.992 us; speedup 1.0000x reference)
//
#include <hip/hip_runtime.h>
#include <hip/hip_bf16.h>

typedef __attribute__((ext_vector_type(8))) short  short8;
typedef __attribute__((ext_vector_type(8))) unsigned short ushort8;
typedef __attribute__((ext_vector_type(4))) float  f32x4;

#define D_DIM 1152     // C*KH*KW
#define O_DIM 256
#define N_TOT 100352   // B*Ho*Wo = 32*56*56
#define T_TERMS 6
#define RR 8
#define R2 72

__device__ __forceinline__ unsigned short f2bf(float f) {
  __hip_bfloat16 h = __float2bfloat16(f);
  return __builtin_bit_cast(unsigned short, h);
}

#define GLOAD_LDS16(g, l)                                              \
  __builtin_amdgcn_global_load_lds(                                    \
      (const __attribute__((address_space(1))) void*)(g),              \
      (__attribute__((address_space(3))) void*)(l), 16, 0, 0)

// ---------------------------------------------------------------------------
// Kernel 1: collapse the T low-rank factorizations into Wt[O][D] (bf16).
// Wt[o][d] = (1/T) * sum_t ( sum_r S1s[t,d,r]*U1s[t,r,o]
//                          + sum_q U2s[t,q,d]*S2s[t,q,o] )
// ---------------------------------------------------------------------------
__global__ void wt_kernel(const float* __restrict__ S1s, const float* __restrict__ U1s,
                          const float* __restrict__ U2s, const float* __restrict__ S2s,
                          unsigned short* __restrict__ Wt) {
  int idx = blockIdx.x * 256 + threadIdx.x;   // idx = o*D + d
  int o = idx / D_DIM;
  int d = idx - o * D_DIM;
  float acc = 0.f;
  for (int t = 0; t < T_TERMS; ++t) {
    const float* s1 = S1s + ((size_t)t * D_DIM + d) * RR;
    const float* u1 = U1s + (size_t)t * RR * O_DIM + o;
#pragma unroll
    for (int r = 0; r < RR; ++r) acc += s1[r] * u1[(size_t)r * O_DIM];
    const float* u2 = U2s + (size_t)t * R2 * D_DIM + d;
    const float* s2 = S2s + (size_t)t * R2 * O_DIM + o;
#pragma unroll 8
    for (int q = 0; q < R2; ++q) acc += u2[(size_t)q * D_DIM] * s2[(size_t)q * O_DIM];
  }
  Wt[(size_t)o * D_DIM + d] = f2bf(acc * (1.0f / 6.0f));
}

// ---------------------------------------------------------------------------
// Kernel 2: explicit im2col, x[B,C,H,W] fp32 -> XW[N][D] bf16.
// d = c*9 + kh*3 + kw (matches Wt's d ordering). Zero padding at borders.
// Each thread emits 8 consecutive d for one n (one ushort8 store).
// ---------------------------------------------------------------------------
__global__ void im2col_kernel(const float* __restrict__ x, unsigned short* __restrict__ XW) {
  long long base = ((long long)blockIdx.x * 256 + threadIdx.x) * 8;
  int n  = (int)(base / D_DIM);
  int d0 = (int)(base - (long long)n * D_DIM);
  int b  = n / 3136;
  int s  = n - b * 3136;
  int oh = s / 56, ow = s - oh * 56;
  const float* xb = x + (size_t)b * 128 * 3136;
  ushort8 v;
#pragma unroll
  for (int i = 0; i < 8; ++i) {
    int d  = d0 + i;
    int c  = d / 9, rr = d - c * 9;
    int kh = rr / 3, kw = rr - kh * 3;
    int ih = oh + kh - 1, iw = ow + kw - 1;
    float f = 0.f;
    if ((unsigned)ih < 56u && (unsigned)iw < 56u)
      f = xb[((size_t)c * 56 + ih) * 56 + iw];
    v[i] = f2bf(f);
  }
  *(ushort8*)(XW + base) = v;
}

// ---------------------------------------------------------------------------
// Kernel 3: GEMM  out[o][n] = sum_k Wt[o][k] * XW[n][k]  (+ 2*bias[o])
// m97 structure: 128x128 tile, BK=64, 4 waves (2x2), mfma_f32_16x16x32_bf16,
// global_load_lds width-16 staging, 2-barrier K-loop (18 steps, exact).
// Output n maps to (b, oh*56+ow): col dimension contiguous -> coalesced stores.
// ---------------------------------------------------------------------------
__global__ __launch_bounds__(256) void gemm_kernel(
    const unsigned short* __restrict__ Wt, const unsigned short* __restrict__ XW,
    const float* __restrict__ bias, float* __restrict__ out) {
  __shared__ __align__(1024) unsigned short lds[(128 + 128) * 64];
  unsigned short* A_lds = lds;             // [128 o][64 k]
  unsigned short* B_lds = lds + 128 * 64;  // [128 n][64 k]

  // XCD swizzle: put the 2 o-tiles of each n-tile adjacent on one XCD
  // (1568 blocks, 1568 % 8 == 0 -> simple bijective form).
  int bid   = blockIdx.x;
  int lid   = (bid & 7) * 196 + (bid >> 3);
  int ntile = lid >> 1, otile = lid & 1;
  int n0 = ntile << 7, o0 = otile << 7;

  int tid  = threadIdx.x;
  int w    = tid >> 6;
  int lane = tid & 63;
  int wr = (w >> 1) << 6;   // wave o-offset within tile
  int wc = (w & 1) << 6;    // wave n-offset within tile

  f32x4 acc[4][4] = {};

  for (int kt = 0; kt < 18; ++kt) {
    const int k0 = kt << 6;
    // ---- stage A and B tiles (each wave: 4 chunks of 1KiB per operand) ----
#pragma unroll
    for (int j = 0; j < 4; ++j) {
      const int chunk = (w << 2) + j;                 // 0..15
      const int row   = (chunk << 3) + (lane >> 3);   // 0..127
      const int kel   = k0 + ((lane & 7) << 3);
      const unsigned short* ga = Wt + (size_t)(o0 + row) * D_DIM + kel;
      const unsigned short* gb = XW + (size_t)(n0 + row) * D_DIM + kel;
      GLOAD_LDS16(ga, A_lds + chunk * 512);
      GLOAD_LDS16(gb, B_lds + chunk * 512);
    }
    __syncthreads();
    // ---- compute: 2 sub-steps of K=32, 16 MFMA each ----
#pragma unroll
    for (int ks = 0; ks < 2; ++ks) {
      const int kof = (ks << 5) + ((lane >> 4) << 3);
      short8 af[4], bfr[4];
#pragma unroll
      for (int m = 0; m < 4; ++m)
        af[m] = *(const short8*)(A_lds + (wr + m * 16 + (lane & 15)) * 64 + kof);
#pragma unroll
      for (int n = 0; n < 4; ++n)
        bfr[n] = *(const short8*)(B_lds + (wc + n * 16 + (lane & 15)) * 64 + kof);
#pragma unroll
      for (int m = 0; m < 4; ++m)
#pragma unroll
        for (int n = 0; n < 4; ++n)
          acc[m][n] = __builtin_amdgcn_mfma_f32_16x16x32_bf16(af[m], bfr[n], acc[m][n], 0, 0, 0);
    }
    __syncthreads();
  }

  // ---- epilogue: D[row=o][col=n]; col=lane&15, row=(lane>>4)*4+reg ----
  const int lr = (lane >> 4) << 2;
  const int lc = lane & 15;
#pragma unroll
  for (int n = 0; n < 4; ++n) {
    const int ng = n0 + wc + n * 16 + lc;
    const int b  = ng / 3136;
    const int s  = ng - b * 3136;
    float* op = out + (size_t)b * (O_DIM * 3136) + s;
#pragma unroll
    for (int m = 0; m < 4; ++m) {
      const int og = o0 + wr + m * 16 + lr;
#pragma unroll
      for (int r = 0; r < 4; ++r)
        op[(size_t)(og + r) * 3136] = acc[m][n][r] + 2.0f * bias[og + r];
    }
  }
}

// ---------------------------------------------------------------------------
extern "C" void kernel_launch(void* const* d_in, const int* in_sizes, int n_in,
                              void* d_out, int out_size, void* d_ws, size_t ws_size,
                              hipStream_t stream) {
  const float* x    = (const float*)d_in[0];
  const float* S1s  = (const float*)d_in[1];
  const float* U1s  = (const float*)d_in[2];
  const float* U2s  = (const float*)d_in[3];
  const float* S2s  = (const float*)d_in[4];
  const float* bias = (const float*)d_in[5];
  float* out = (float*)d_out;

  // workspace layout: XW bf16 [100352][1152] at 0, Wt bf16 [256][1152] after.
  unsigned short* XW = (unsigned short*)d_ws;
  unsigned short* Wt = (unsigned short*)((char*)d_ws + (size_t)N_TOT * D_DIM * 2);

  wt_kernel<<<dim3((O_DIM * D_DIM) / 256), dim3(256), 0, stream>>>(S1s, U1s, U2s, S2s, Wt);
  im2col_kernel<<<dim3(N_TOT * D_DIM / (256 * 8)), dim3(256), 0, stream>>>(x, XW);
  gemm_kernel<<<dim3(1568), dim3(256), 0, stream>>>(Wt, XW, bias, out);
}

// Round 2
// 251.121 us; speedup vs baseline: 2.2658x; 2.2658x over previous
//
#include <hip/hip_runtime.h>
#include <hip/hip_bf16.h>

typedef __attribute__((ext_vector_type(8))) short  short8;
typedef __attribute__((ext_vector_type(8))) unsigned short ushort8;
typedef __attribute__((ext_vector_type(4))) float  f32x4;

#define D_DIM 1152     // C*KH*KW
#define O_DIM 256
#define N_TOT 100352   // B*Ho*Wo = 32*56*56
#define T_TERMS 6
#define RR 8
#define R2 72

// padded NHWC transpose of x: [32][58][58][128] bf16 (zero borders)
#define XT_H 58
#define XT_ROW (58 * 128)   // elems per (b,ih) row-plane

__device__ __forceinline__ unsigned short f2bf(float f) {
  __hip_bfloat16 h = __float2bfloat16(f);
  return __builtin_bit_cast(unsigned short, h);
}

#define GLOAD_LDS16(g, l)                                              \
  __builtin_amdgcn_global_load_lds(                                    \
      (const __attribute__((address_space(1))) void*)(g),              \
      (__attribute__((address_space(3))) void*)(l), 16, 0, 0)

// ---------------------------------------------------------------------------
// Kernel 1: collapse T low-rank factorizations into Wt[O][D] bf16,
// with K reordered: d_new = (kh*3+kw)*128 + c ;  d_old = c*9 + (kh*3+kw)
// ---------------------------------------------------------------------------
__global__ void wt_kernel(const float* __restrict__ S1s, const float* __restrict__ U1s,
                          const float* __restrict__ U2s, const float* __restrict__ S2s,
                          unsigned short* __restrict__ Wt) {
  int idx = blockIdx.x * 256 + threadIdx.x;   // idx = o*D + d_new
  int o  = idx / D_DIM;
  int dn = idx - o * D_DIM;
  int rr = dn >> 7;          // kh*3+kw
  int c  = dn & 127;
  int d  = c * 9 + rr;       // original d for factor indexing
  float acc = 0.f;
  for (int t = 0; t < T_TERMS; ++t) {
    const float* s1 = S1s + ((size_t)t * D_DIM + d) * RR;
    const float* u1 = U1s + (size_t)t * RR * O_DIM + o;
#pragma unroll
    for (int r = 0; r < RR; ++r) acc += s1[r] * u1[(size_t)r * O_DIM];
    const float* u2 = U2s + (size_t)t * R2 * D_DIM + d;
    const float* s2 = S2s + (size_t)t * R2 * O_DIM + o;
#pragma unroll 8
    for (int q = 0; q < R2; ++q) acc += u2[(size_t)q * D_DIM] * s2[(size_t)q * O_DIM];
  }
  Wt[(size_t)o * D_DIM + dn] = f2bf(acc * (1.0f / 6.0f));
}

// ---------------------------------------------------------------------------
// Kernel 2: pad+transpose  x[B,C,H,W] fp32  ->  x_t[b][ih][iw][c] bf16
// (ih,iw in padded 58x58 coords; borders are zero). LDS-staged transpose:
// reads coalesced along w, writes coalesced along c.
// ---------------------------------------------------------------------------
__global__ __launch_bounds__(256) void pad_kernel(const float* __restrict__ x,
                                                  unsigned short* __restrict__ xt) {
  int blk = blockIdx.x;            // b*58 + ih
  int b = blk / XT_H, ih = blk - b * XT_H;
  unsigned short* dst = xt + (size_t)blk * XT_ROW;
  int tid = threadIdx.x;

  if (ih == 0 || ih == XT_H - 1) {
    ushort8 z;
#pragma unroll
    for (int q = 0; q < 8; ++q) z[q] = 0;
    for (int i = tid; i < XT_ROW / 8; i += 256) ((ushort8*)dst)[i] = z;
    return;
  }

  __shared__ unsigned short lds[128 * 58];   // [c][w], stride 58 breaks bank collisions
  int h = ih - 1;
  const float* xb = x + (size_t)b * 128 * 3136 + (size_t)h * 56;
  // read 128c x 56w, coalesced along w
#pragma unroll 4
  for (int r = 0; r < 28; ++r) {
    int idx = r * 256 + tid;       // 0..7167
    int c = idx / 56, w2 = idx - c * 56;
    lds[c * 58 + w2] = f2bf(xb[(size_t)c * 3136 + w2]);
  }
  __syncthreads();
  // write 58 iw x 128 c, coalesced along c
#pragma unroll 4
  for (int r = 0; r < 29; ++r) {
    int idx = r * 256 + tid;       // 0..7423
    int iw = idx >> 7, c = idx & 127;
    unsigned short v = 0;
    if (iw >= 1 && iw <= 56) v = lds[c * 58 + (iw - 1)];
    dst[idx] = v;
  }
}

// ---------------------------------------------------------------------------
// Kernel 3: fused implicit-im2col GEMM
//   out[o][n] = sum_d Wt[o][d] * x_t[b(n), oh(n)+kh, ow(n)+kw, c] + 2*bias[o]
// m97 structure: 128x128 tile, BK=64 (= one (kh,kw) half-channel slice),
// 4 waves (2x2), mfma 16x16x32 bf16, global_load_lds width 16.
// Per-lane B base pointers precomputed once; per K-step adds constexpr offset.
// ---------------------------------------------------------------------------
__global__ __launch_bounds__(256) void gemm_kernel(
    const unsigned short* __restrict__ Wt, const unsigned short* __restrict__ xt,
    const float* __restrict__ bias, float* __restrict__ out) {
  __shared__ __align__(1024) unsigned short lds[(128 + 128) * 64];
  unsigned short* A_lds = lds;             // [128 o][64 k]
  unsigned short* B_lds = lds + 128 * 64;  // [128 n][64 k]

  // XCD swizzle (1568 % 8 == 0 -> bijective): pair the 2 o-tiles per n-tile.
  int bid   = blockIdx.x;
  int lid   = (bid & 7) * 196 + (bid >> 3);
  int ntile = lid >> 1, otile = lid & 1;
  int n0 = ntile << 7, o0 = otile << 7;

  int tid  = threadIdx.x;
  int w    = tid >> 6;
  int lane = tid & 63;
  int wr = (w >> 1) << 6;
  int wc = (w & 1) << 6;

  // per-chunk staging pointers (fixed across K-steps)
  const unsigned short* ptrA[4];
  const unsigned short* ptrB[4];
#pragma unroll
  for (int j = 0; j < 4; ++j) {
    int chunk = (w << 2) + j;                 // 0..15
    int row   = (chunk << 3) + (lane >> 3);   // 0..127
    ptrA[j] = Wt + (size_t)(o0 + row) * D_DIM + ((lane & 7) << 3);
    int n_g = n0 + row;
    int b   = n_g / 3136;
    int s   = n_g - b * 3136;
    int oh  = s / 56, ow = s - oh * 56;
    // base at (kh=0,kw=0): padded coords (ih=oh, iw=ow)
    ptrB[j] = xt + (((size_t)b * XT_H + oh) * XT_H + ow) * 128 + ((lane & 7) << 3);
  }

  f32x4 acc[4][4] = {};

#pragma unroll
  for (int kt = 0; kt < 18; ++kt) {
    const int rr   = kt >> 1;
    const int kh   = rr / 3, kw = rr - kh * 3;
    const int koff = (kh * XT_H + kw) * 128 + ((kt & 1) << 6);  // constexpr after unroll
    const int k0   = kt << 6;
#pragma unroll
    for (int j = 0; j < 4; ++j) {
      const int chunk = (w << 2) + j;
      GLOAD_LDS16(ptrA[j] + k0,   A_lds + chunk * 512);
      GLOAD_LDS16(ptrB[j] + koff, B_lds + chunk * 512);
    }
    __syncthreads();
#pragma unroll
    for (int ks = 0; ks < 2; ++ks) {
      const int kof = (ks << 5) + ((lane >> 4) << 3);
      short8 af[4], bfr[4];
#pragma unroll
      for (int m = 0; m < 4; ++m)
        af[m] = *(const short8*)(A_lds + (wr + m * 16 + (lane & 15)) * 64 + kof);
#pragma unroll
      for (int n = 0; n < 4; ++n)
        bfr[n] = *(const short8*)(B_lds + (wc + n * 16 + (lane & 15)) * 64 + kof);
#pragma unroll
      for (int m = 0; m < 4; ++m)
#pragma unroll
        for (int n = 0; n < 4; ++n)
          acc[m][n] = __builtin_amdgcn_mfma_f32_16x16x32_bf16(af[m], bfr[n], acc[m][n], 0, 0, 0);
    }
    __syncthreads();
  }

  // epilogue: D[row=o][col=n]; col=lane&15, row=(lane>>4)*4+reg
  const int lr = (lane >> 4) << 2;
  const int lc = lane & 15;
#pragma unroll
  for (int n = 0; n < 4; ++n) {
    const int ng = n0 + wc + n * 16 + lc;
    const int b  = ng / 3136;
    const int s  = ng - b * 3136;
    float* op = out + (size_t)b * (O_DIM * 3136) + s;
#pragma unroll
    for (int m = 0; m < 4; ++m) {
      const int og = o0 + wr + m * 16 + lr;
#pragma unroll
      for (int r = 0; r < 4; ++r)
        op[(size_t)(og + r) * 3136] = acc[m][n][r] + 2.0f * bias[og + r];
    }
  }
}

// ---------------------------------------------------------------------------
extern "C" void kernel_launch(void* const* d_in, const int* in_sizes, int n_in,
                              void* d_out, int out_size, void* d_ws, size_t ws_size,
                              hipStream_t stream) {
  const float* x    = (const float*)d_in[0];
  const float* S1s  = (const float*)d_in[1];
  const float* U1s  = (const float*)d_in[2];
  const float* U2s  = (const float*)d_in[3];
  const float* S2s  = (const float*)d_in[4];
  const float* bias = (const float*)d_in[5];
  float* out = (float*)d_out;

  // workspace: x_t bf16 [32][58][58][128] (27.6 MB), then Wt bf16 [256][1152]
  unsigned short* xt = (unsigned short*)d_ws;
  unsigned short* Wt = (unsigned short*)((char*)d_ws + (size_t)32 * XT_H * XT_ROW * 2);

  pad_kernel<<<dim3(32 * XT_H), dim3(256), 0, stream>>>(x, xt);
  wt_kernel<<<dim3((O_DIM * D_DIM) / 256), dim3(256), 0, stream>>>(S1s, U1s, U2s, S2s, Wt);
  gemm_kernel<<<dim3(1568), dim3(256), 0, stream>>>(Wt, xt, bias, out);
}

// Round 4
// 137.145 us; speedup vs baseline: 4.1488x; 1.8311x over previous
//
#include <hip/hip_runtime.h>
#include <hip/hip_bf16.h>

typedef __attribute__((ext_vector_type(8))) short  short8;
typedef __attribute__((ext_vector_type(8))) unsigned short ushort8;
typedef __attribute__((ext_vector_type(4))) unsigned short usv4;
typedef __attribute__((ext_vector_type(4))) float  f32x4;

#define D_DIM 1152     // C*KH*KW
#define O_DIM 256
#define N_TOT 100352   // B*Ho*Wo = 32*56*56
#define K_CAT 480      // 48 (term1: T*R) + 432 (term2: T*R2)

// padded NHWC transpose of x: [32][58][58][128] bf16 (zero borders)
#define XT_H 58
#define XT_ROW (58 * 128)

__device__ __forceinline__ unsigned short f2bf(float f) {
  __hip_bfloat16 h = __float2bfloat16(f);
  return __builtin_bit_cast(unsigned short, h);
}

#define GLOAD_LDS16(g, l)                                              \
  __builtin_amdgcn_global_load_lds(                                    \
      (const __attribute__((address_space(1))) void*)(g),              \
      (__attribute__((address_space(3))) void*)(l), 16, 0, 0)

// ---------------------------------------------------------------------------
// Kernel 1 (v2): Wt[o][dn] = (1/T) * sum_k Acat[k][o] * Bcat[k][dn]
// as an LDS-tiled fp32 block-GEMM. dn = (kh*3+kw)*128 + c ; d_old = c*9 + rr.
// Tile 64o x 64dn, K chunks of 32, 4x4 register tile per thread.
// ---------------------------------------------------------------------------
__global__ __launch_bounds__(256) void wt_kernel(
    const float* __restrict__ S1s, const float* __restrict__ U1s,
    const float* __restrict__ U2s, const float* __restrict__ S2s,
    unsigned short* __restrict__ Wt) {
  __shared__ float A_lds[32][64];   // [kk][o]
  __shared__ float B_lds[32][64];   // [kk][dn]

  const int bo = blockIdx.x & 3;          // o-tile 0..3
  const int bd = blockIdx.x >> 2;         // dn-tile 0..17
  const int o0  = bo << 6;
  const int dn0 = bd << 6;
  const int rr  = dn0 >> 7;               // kh*3+kw (uniform in tile: 64 | 128)
  const int c0  = dn0 & 127;

  const int tid = threadIdx.x;
  const int ty = tid >> 4, tx = tid & 15; // 16x16 thread grid

  float acc[4][4] = {};

  for (int kc = 0; kc < 15; ++kc) {
#pragma unroll
    for (int e = 0; e < 8; ++e) {
      const int li = e * 256 + tid;       // 0..2047
      const int kk = li >> 6;             // wave-uniform
      const int xx = li & 63;
      const int k  = kc * 32 + kk;
      float av, bv;
      if (k < 48) {
        av = U1s[k * O_DIM + o0 + xx];
        const int d_old = (c0 + xx) * 9 + rr;
        bv = S1s[(size_t)((k >> 3) * D_DIM + d_old) * 8 + (k & 7)];
      } else {
        const int kq = k - 48;
        av = S2s[(size_t)kq * O_DIM + o0 + xx];
        const int d_old = (c0 + xx) * 9 + rr;
        bv = U2s[(size_t)kq * D_DIM + d_old];
      }
      A_lds[kk][xx] = av;
      B_lds[kk][xx] = bv;
    }
    __syncthreads();
#pragma unroll
    for (int kk = 0; kk < 32; ++kk) {
      f32x4 a = *(const f32x4*)&A_lds[kk][ty << 2];
      f32x4 b = *(const f32x4*)&B_lds[kk][tx << 2];
#pragma unroll
      for (int i = 0; i < 4; ++i)
#pragma unroll
        for (int j = 0; j < 4; ++j)
          acc[i][j] += a[i] * b[j];
    }
    __syncthreads();
  }

#pragma unroll
  for (int i = 0; i < 4; ++i) {
    usv4 v;
#pragma unroll
    for (int j = 0; j < 4; ++j) v[j] = f2bf(acc[i][j] * (1.0f / 6.0f));
    *(usv4*)(Wt + (size_t)(o0 + (ty << 2) + i) * D_DIM + dn0 + (tx << 2)) = v;
  }
}

// ---------------------------------------------------------------------------
// Kernel 2: pad+transpose  x[B,C,H,W] fp32  ->  x_t[b][ih][iw][c] bf16
// ---------------------------------------------------------------------------
__global__ __launch_bounds__(256) void pad_kernel(const float* __restrict__ x,
                                                  unsigned short* __restrict__ xt) {
  int blk = blockIdx.x;            // b*58 + ih
  int b = blk / XT_H, ih = blk - b * XT_H;
  unsigned short* dst = xt + (size_t)blk * XT_ROW;
  int tid = threadIdx.x;

  if (ih == 0 || ih == XT_H - 1) {
    ushort8 z;
#pragma unroll
    for (int q = 0; q < 8; ++q) z[q] = 0;
    for (int i = tid; i < XT_ROW / 8; i += 256) ((ushort8*)dst)[i] = z;
    return;
  }

  __shared__ unsigned short lds[128 * 58];
  int h = ih - 1;
  const float* xb = x + (size_t)b * 128 * 3136 + (size_t)h * 56;
#pragma unroll 4
  for (int r = 0; r < 28; ++r) {
    int idx = r * 256 + tid;
    int c = idx / 56, w2 = idx - c * 56;
    lds[c * 58 + w2] = f2bf(xb[(size_t)c * 3136 + w2]);
  }
  __syncthreads();
#pragma unroll 4
  for (int r = 0; r < 29; ++r) {
    int idx = r * 256 + tid;
    int iw = idx >> 7, c = idx & 127;
    unsigned short v = 0;
    if (iw >= 1 && iw <= 56) v = lds[c * 58 + (iw - 1)];
    dst[idx] = v;
  }
}

// ---------------------------------------------------------------------------
// Kernel 3: fused implicit-im2col GEMM (m97 structure, unchanged from R2)
// ---------------------------------------------------------------------------
__global__ __launch_bounds__(256) void gemm_kernel(
    const unsigned short* __restrict__ Wt, const unsigned short* __restrict__ xt,
    const float* __restrict__ bias, float* __restrict__ out) {
  __shared__ __align__(1024) unsigned short lds[(128 + 128) * 64];
  unsigned short* A_lds = lds;
  unsigned short* B_lds = lds + 128 * 64;

  int bid   = blockIdx.x;
  int lid   = (bid & 7) * 196 + (bid >> 3);
  int ntile = lid >> 1, otile = lid & 1;
  int n0 = ntile << 7, o0 = otile << 7;

  int tid  = threadIdx.x;
  int w    = tid >> 6;
  int lane = tid & 63;
  int wr = (w >> 1) << 6;
  int wc = (w & 1) << 6;

  const unsigned short* ptrA[4];
  const unsigned short* ptrB[4];
#pragma unroll
  for (int j = 0; j < 4; ++j) {
    int chunk = (w << 2) + j;
    int row   = (chunk << 3) + (lane >> 3);
    ptrA[j] = Wt + (size_t)(o0 + row) * D_DIM + ((lane & 7) << 3);
    int n_g = n0 + row;
    int b   = n_g / 3136;
    int s   = n_g - b * 3136;
    int oh  = s / 56, ow = s - oh * 56;
    ptrB[j] = xt + (((size_t)b * XT_H + oh) * XT_H + ow) * 128 + ((lane & 7) << 3);
  }

  f32x4 acc[4][4] = {};

#pragma unroll
  for (int kt = 0; kt < 18; ++kt) {
    const int rr   = kt >> 1;
    const int kh   = rr / 3, kw = rr - kh * 3;
    const int koff = (kh * XT_H + kw) * 128 + ((kt & 1) << 6);
    const int k0   = kt << 6;
#pragma unroll
    for (int j = 0; j < 4; ++j) {
      const int chunk = (w << 2) + j;
      GLOAD_LDS16(ptrA[j] + k0,   A_lds + chunk * 512);
      GLOAD_LDS16(ptrB[j] + koff, B_lds + chunk * 512);
    }
    __syncthreads();
#pragma unroll
    for (int ks = 0; ks < 2; ++ks) {
      const int kof = (ks << 5) + ((lane >> 4) << 3);
      short8 af[4], bfr[4];
#pragma unroll
      for (int m = 0; m < 4; ++m)
        af[m] = *(const short8*)(A_lds + (wr + m * 16 + (lane & 15)) * 64 + kof);
#pragma unroll
      for (int n = 0; n < 4; ++n)
        bfr[n] = *(const short8*)(B_lds + (wc + n * 16 + (lane & 15)) * 64 + kof);
#pragma unroll
      for (int m = 0; m < 4; ++m)
#pragma unroll
        for (int n = 0; n < 4; ++n)
          acc[m][n] = __builtin_amdgcn_mfma_f32_16x16x32_bf16(af[m], bfr[n], acc[m][n], 0, 0, 0);
    }
    __syncthreads();
  }

  const int lr = (lane >> 4) << 2;
  const int lc = lane & 15;
#pragma unroll
  for (int n = 0; n < 4; ++n) {
    const int ng = n0 + wc + n * 16 + lc;
    const int b  = ng / 3136;
    const int s  = ng - b * 3136;
    float* op = out + (size_t)b * (O_DIM * 3136) + s;
#pragma unroll
    for (int m = 0; m < 4; ++m) {
      const int og = o0 + wr + m * 16 + lr;
#pragma unroll
      for (int r = 0; r < 4; ++r)
        op[(size_t)(og + r) * 3136] = acc[m][n][r] + 2.0f * bias[og + r];
    }
  }
}

// ---------------------------------------------------------------------------
extern "C" void kernel_launch(void* const* d_in, const int* in_sizes, int n_in,
                              void* d_out, int out_size, void* d_ws, size_t ws_size,
                              hipStream_t stream) {
  const float* x    = (const float*)d_in[0];
  const float* S1s  = (const float*)d_in[1];
  const float* U1s  = (const float*)d_in[2];
  const float* U2s  = (const float*)d_in[3];
  const float* S2s  = (const float*)d_in[4];
  const float* bias = (const float*)d_in[5];
  float* out = (float*)d_out;

  unsigned short* xt = (unsigned short*)d_ws;
  unsigned short* Wt = (unsigned short*)((char*)d_ws + (size_t)32 * XT_H * XT_ROW * 2);

  pad_kernel<<<dim3(32 * XT_H), dim3(256), 0, stream>>>(x, xt);
  wt_kernel<<<dim3(72), dim3(256), 0, stream>>>(S1s, U1s, U2s, S2s, Wt);
  gemm_kernel<<<dim3(1568), dim3(256), 0, stream>>>(Wt, xt, bias, out);
}